// Round 5
// baseline (130.777 us; speedup 1.0000x reference)
//
#include <hip/hip_runtime.h>
#include <math.h>

// R4 (precomposed-weights) + three changes:
//  1. persistent grid-stride launch, 2048 blocks (8 blocks/CU -> 32 waves/CU)
//  2. ALL scale constants folded into precomposed weight copies in d_ws
//  3. smear exp factorization: s[i] = E0 * r^i * K[i^2], 2 exps per array
// All ALU scalar fmaf/mul (gfx950 fast path).

#define WS_W12  0     // [20][5][9] *i21*i105          = 900
#define WS_WV   900   // [5][9]     *i21*i105*i3       = 45
#define WS_WS   945   // [20]       *i21*i50           = 20
#define WS_CS   965   // scalar     *i21*i50*i3        = 1
#define WS_SVV  966   // [5][5]     *i10               = 25
#define WS_VSV  991   // [4][5]     *i10               = 20
#define WS_VVV1 1011  // [5]        *i10*i2            = 5
#define WS_VSV2 1016  // [5][5]     *i50               = 25
#define WS_VVV2 1041  // [5]        *i2*i50            = 5
#define WS_VVO2 1046  // [5][9]     *i3*i105           = 45
#define WS_TOT  1091

__global__ __launch_bounds__(256) void fds_precompose(
    const float* __restrict__ W1_sso, const float* __restrict__ W1_svv,
    const float* __restrict__ W1_vsv, const float* __restrict__ W1_vvo,
    const float* __restrict__ W1_vvv, const float* __restrict__ W2_sso,
    const float* __restrict__ W2_svv, const float* __restrict__ W2_vsv,
    const float* __restrict__ W2_vvo, const float* __restrict__ W2_vvv,
    float* __restrict__ ws)
{
    const float I2 = 0.70710678118654752f, I3 = 0.57735026918962576f;
    const float I10 = 0.31622776601683794f, I21 = 0.21821789023599239f;
    const float I105 = 0.09759000729485332f, I50 = 0.14142135623730950f;
    int tid = threadIdx.x;
    for (int idx = tid; idx < 900; idx += 256) {
        int o = idx % 9, j3 = (idx / 9) % 5, ij = idx / 45;
        float acc = 0.f;
        for (int k2 = 0; k2 < 20; k2++)
            acc = fmaf(W1_sso[ij * 20 + k2], W2_sso[(k2 * 5 + j3) * 9 + o], acc);
        ws[WS_W12 + idx] = acc * (I21 * I105);
    }
    for (int idx = tid; idx < 45; idx += 256) {
        int o = idx % 9, j3 = idx / 9;
        float acc = 0.f;
        for (int k2 = 0; k2 < 20; k2++)
            acc = fmaf(W1_vvo[k2], W2_sso[(k2 * 5 + j3) * 9 + o], acc);
        ws[WS_WV + idx] = acc * (I21 * I105 * I3);
    }
    for (int idx = tid; idx < 20; idx += 256) {
        float acc = 0.f;
        for (int k2 = 0; k2 < 20; k2++)
            acc = fmaf(W1_sso[idx * 20 + k2], W2_svv[k2], acc);
        ws[WS_WS + idx] = acc * (I21 * I50);
    }
    if (tid == 0) {
        float acc = 0.f;
        for (int k2 = 0; k2 < 20; k2++) acc = fmaf(W1_vvo[k2], W2_svv[k2], acc);
        ws[WS_CS] = acc * (I21 * I50 * I3);
    }
    for (int idx = tid; idx < 25; idx += 256) ws[WS_SVV + idx] = W1_svv[idx] * I10;
    for (int idx = tid; idx < 20; idx += 256) ws[WS_VSV + idx] = W1_vsv[idx] * I10;
    for (int idx = tid; idx < 5; idx += 256)  ws[WS_VVV1 + idx] = W1_vvv[idx] * (I10 * I2);
    for (int idx = tid; idx < 25; idx += 256) ws[WS_VSV2 + idx] = W2_vsv[idx] * I50;
    for (int idx = tid; idx < 5; idx += 256)  ws[WS_VVV2 + idx] = W2_vvv[idx] * (I2 * I50);
    for (int idx = tid; idx < 45; idx += 256) ws[WS_VVO2 + idx] = W2_vvo[idx] * (I3 * I105);
}

__global__ __launch_bounds__(256, 8) void fds_kernel(
    const float* __restrict__ lig, const float* __restrict__ rec,
    const float* __restrict__ ws, float* __restrict__ out, int E)
{
    const float C5 = -0.32f;          // -0.5 / 1.25^2
    const float C4 = -0.18f;          // -0.5 / (5/3)^2
    const float EK1  = 0.60653065971263342f;   // e^-0.5
    const float EK4  = 0.13533528323661270f;   // e^-2
    const float EK9  = 0.011108996538242306f;  // e^-4.5
    const float EK16 = 3.3546262790251185e-4f; // e^-8

    const float* __restrict__ W12  = ws + WS_W12;
    const float* __restrict__ WV   = ws + WS_WV;
    const float* __restrict__ WSp  = ws + WS_WS;
    const float* __restrict__ SVV  = ws + WS_SVV;
    const float* __restrict__ VSV  = ws + WS_VSV;
    const float* __restrict__ VVV1 = ws + WS_VVV1;
    const float* __restrict__ VSV2 = ws + WS_VSV2;
    const float* __restrict__ VVV2 = ws + WS_VVV2;
    const float* __restrict__ VVO2 = ws + WS_VVO2;

    int t0 = blockIdx.x * blockDim.x + threadIdx.x;
    int stride = gridDim.x * blockDim.x;
    size_t E3 = (size_t)E * 3;

    for (int e = t0; e < E; e += stride) {
        const float4* lp = (const float4*)lig + 3 * (size_t)e;
        const float4* rp = (const float4*)rec + 3 * (size_t)e;
        float4 l0 = lp[0], l1 = lp[1], l2 = lp[2];
        float4 r0 = rp[0], r1 = rp[1], r2 = rp[2];

        float e1x = l0.w - r0.w, e1y = l1.x - r1.x, e1z = l1.y - r1.y;
        float e2x = l1.z - r1.z, e2y = l1.w - r1.w, e2z = l2.x - r2.x;
        float e3x = l2.y - r2.y, e3y = l2.z - r2.z, e3z = l2.w - r2.w;

        float q1 = fmaf(e1x, e1x, fmaf(e1y, e1y, e1z * e1z)) + 1e-12f;
        float q2 = fmaf(e2x, e2x, fmaf(e2y, e2y, e2z * e2z)) + 1e-12f;
        float q3 = fmaf(e3x, e3x, fmaf(e3y, e3y, e3z * e3z)) + 1e-12f;
        float ri1 = rsqrtf(q1), ri2 = rsqrtf(q2), ri3 = rsqrtf(q3);
        float d1 = q1 * ri1, d2 = q2 * ri2, d3 = q3 * ri3;
        float v1x = e1x * ri1, v1y = e1y * ri1, v1z = e1z * ri1;
        float v2x = e2x * ri2, v2y = e2y * ri2, v2z = e2z * ri2;
        float v3x = e3x * ri3, v3y = e3y * ri3, v3z = e3z * ri3;

        // smear: s[i] = exp(C*(d - h*i)^2) = E0 * r^i * K[i^2]
        float s1[5], s3[5], s2[4];
        {
            float E0 = __expf(C5 * d1 * d1), r = __expf(0.8f * d1);
            float rr = r * r, u = E0 * r, v = E0 * rr;
            s1[0] = E0; s1[1] = u * EK1; s1[2] = v * EK4;
            s1[3] = v * r * EK9; s1[4] = v * rr * EK16;
        }
        {
            float E0 = __expf(C5 * d3 * d3), r = __expf(0.8f * d3);
            float rr = r * r, u = E0 * r, v = E0 * rr;
            s3[0] = E0; s3[1] = u * EK1; s3[2] = v * EK4;
            s3[3] = v * r * EK9; s3[4] = v * rr * EK16;
        }
        {
            float E0 = __expf(C4 * d2 * d2), r = __expf(0.6f * d2);
            float rr = r * r;
            s2[0] = E0; s2[1] = E0 * r * EK1; s2[2] = E0 * rr * EK4;
            s2[3] = E0 * rr * r * EK9;
        }

        float dot12 = fmaf(v1x, v2x, fmaf(v1y, v2y, v1z * v2z));  // raw
        float cr12x = v1y * v2z - v1z * v2y;                       // raw
        float cr12y = v1z * v2x - v1x * v2z;
        float cr12z = v1x * v2y - v1y * v2x;

        // layer 1 vector path (scales folded into SVV/VSV/VVV1)
        float A[5], B[5];
#pragma unroll
        for (int k = 0; k < 5; k++) {
            float a = 0.f, b = 0.f;
#pragma unroll
            for (int i = 0; i < 5; i++) a = fmaf(s1[i], SVV[i * 5 + k], a);
#pragma unroll
            for (int j = 0; j < 4; j++) b = fmaf(s2[j], VSV[j * 5 + k], b);
            A[k] = a; B[k] = b;
        }
        float ov[5][3];
#pragma unroll
        for (int k = 0; k < 5; k++) {
            float w = VVV1[k];
            ov[k][0] = fmaf(A[k], v2x, fmaf(B[k], v1x, cr12x * w));
            ov[k][1] = fmaf(A[k], v2y, fmaf(B[k], v1y, cr12y * w));
            ov[k][2] = fmaf(A[k], v2z, fmaf(B[k], v1z, cr12z * w));
        }

        float dot2[5];
#pragma unroll
        for (int k = 0; k < 5; k++)
            dot2[k] = fmaf(ov[k][0], v3x, fmaf(ov[k][1], v3y, ov[k][2] * v3z)); // raw

        float accs[9];
#pragma unroll
        for (int o = 0; o < 9; o++) accs[o] = 0.f;
#pragma unroll
        for (int k = 0; k < 5; k++)
#pragma unroll
            for (int o = 0; o < 9; o++) accs[o] = fmaf(dot2[k], VVO2[k * 9 + o], accs[o]);

        float av0 = 0.f, av1 = 0.f, av2 = 0.f;
#pragma unroll
        for (int k = 0; k < 5; k++) {
            float c = 0.f;
#pragma unroll
            for (int j = 0; j < 5; j++) c = fmaf(s3[j], VSV2[k * 5 + j], c);
            float w = VVV2[k];
            float cx = ov[k][1] * v3z - ov[k][2] * v3y;  // raw cross
            float cy = ov[k][2] * v3x - ov[k][0] * v3z;
            float cz = ov[k][0] * v3y - ov[k][1] * v3x;
            av0 = fmaf(ov[k][0], c, fmaf(cx, w, av0));
            av1 = fmaf(ov[k][1], c, fmaf(cy, w, av1));
            av2 = fmaf(ov[k][2], c, fmaf(cz, w, av2));
        }
        // ov dead from here

        float p12[20];
#pragma unroll
        for (int i = 0; i < 5; i++)
#pragma unroll
            for (int j = 0; j < 4; j++) p12[i * 4 + j] = s1[i] * s2[j];

        float S = dot12 * ws[WS_CS];
#pragma unroll
        for (int ij = 0; ij < 20; ij++) S = fmaf(p12[ij], WSp[ij], S);
        av0 = fmaf(S, v3x, av0);
        av1 = fmaf(S, v3y, av1);
        av2 = fmaf(S, v3z, av2);

#pragma unroll
        for (int j3 = 0; j3 < 5; j3++) {
            float fv = dot12 * s3[j3];
            const float* w = WV + j3 * 9;
#pragma unroll
            for (int o = 0; o < 9; o++) accs[o] = fmaf(fv, w[o], accs[o]);
        }
#pragma unroll
        for (int ij = 0; ij < 20; ij++) {
            float p = p12[ij];
#pragma unroll
            for (int j3 = 0; j3 < 5; j3++) {
                float f = p * s3[j3];
                const float* w = W12 + (ij * 5 + j3) * 9;
#pragma unroll
                for (int o = 0; o < 9; o++) accs[o] = fmaf(f, w[o], accs[o]);
            }
        }

        size_t b = (size_t)e * 3;
        out[b + 0]          = accs[0];   // s_rot
        out[b + 1]          = accs[1];
        out[b + 2]          = accs[2];
        out[E3 + b + 0]     = accs[3];   // s_tr
        out[E3 + b + 1]     = accs[4];
        out[E3 + b + 2]     = accs[5];
        out[2 * E3 + b + 0] = accs[6];   // t_rot
        out[2 * E3 + b + 1] = accs[7];
        out[2 * E3 + b + 2] = accs[8];
        out[3 * E3 + b + 0] = av0;       // t_tr
        out[3 * E3 + b + 1] = av1;
        out[3 * E3 + b + 2] = av2;
    }
}

extern "C" void kernel_launch(void* const* d_in, const int* in_sizes, int n_in,
                              void* d_out, int out_size, void* d_ws, size_t ws_size,
                              hipStream_t stream) {
    const float* lig    = (const float*)d_in[0];
    const float* rec    = (const float*)d_in[1];
    const float* W1_sso = (const float*)d_in[2];
    const float* W1_svv = (const float*)d_in[3];
    const float* W1_vsv = (const float*)d_in[4];
    const float* W1_vvo = (const float*)d_in[5];
    const float* W1_vvv = (const float*)d_in[6];
    const float* W2_sso = (const float*)d_in[7];
    const float* W2_svv = (const float*)d_in[8];
    const float* W2_vsv = (const float*)d_in[9];
    const float* W2_vvo = (const float*)d_in[10];
    const float* W2_vvv = (const float*)d_in[11];
    float* ws = (float*)d_ws;

    fds_precompose<<<1, 256, 0, stream>>>(W1_sso, W1_svv, W1_vsv, W1_vvo, W1_vvv,
                                          W2_sso, W2_svv, W2_vsv, W2_vvo, W2_vvv, ws);

    int E = in_sizes[0] / 12;  // N*3 / 12 = N/4
    int blocks = (E + 255) / 256;
    if (blocks > 2048) blocks = 2048;   // 8 blocks/CU x 256 CU, grid-stride
    fds_kernel<<<blocks, 256, 0, stream>>>(lig, rec, ws, (float*)d_out, E);
}

// Round 6
// 120.884 us; speedup vs baseline: 1.0818x; 1.0818x over previous
//
#include <hip/hip_runtime.h>
#include <math.h>

// R5 minus the toxic __launch_bounds__(256,8) (it forced a 64-VGPR budget ->
// VGPR=32 + full scratch spill, +275MB HBM traffic). Keeps:
//  1. persistent grid-stride launch, 2048 blocks
//  2. ALL scale constants folded into precomposed weight copies in d_ws
//  3. smear exp factorization: s[i] = E0 * r^i * K[i^2], 2 exps per array
// All ALU scalar fmaf/mul (gfx950 fast path). Target VGPR ~36-48, no spills.

#define WS_W12  0     // [20][5][9] *i21*i105          = 900
#define WS_WV   900   // [5][9]     *i21*i105*i3       = 45
#define WS_WS   945   // [20]       *i21*i50           = 20
#define WS_CS   965   // scalar     *i21*i50*i3        = 1
#define WS_SVV  966   // [5][5]     *i10               = 25
#define WS_VSV  991   // [4][5]     *i10               = 20
#define WS_VVV1 1011  // [5]        *i10*i2            = 5
#define WS_VSV2 1016  // [5][5]     *i50               = 25
#define WS_VVV2 1041  // [5]        *i2*i50            = 5
#define WS_VVO2 1046  // [5][9]     *i3*i105           = 45
#define WS_TOT  1091

__global__ __launch_bounds__(256) void fds_precompose(
    const float* __restrict__ W1_sso, const float* __restrict__ W1_svv,
    const float* __restrict__ W1_vsv, const float* __restrict__ W1_vvo,
    const float* __restrict__ W1_vvv, const float* __restrict__ W2_sso,
    const float* __restrict__ W2_svv, const float* __restrict__ W2_vsv,
    const float* __restrict__ W2_vvo, const float* __restrict__ W2_vvv,
    float* __restrict__ ws)
{
    const float I2 = 0.70710678118654752f, I3 = 0.57735026918962576f;
    const float I10 = 0.31622776601683794f, I21 = 0.21821789023599239f;
    const float I105 = 0.09759000729485332f, I50 = 0.14142135623730950f;
    int tid = threadIdx.x;
    for (int idx = tid; idx < 900; idx += 256) {
        int o = idx % 9, j3 = (idx / 9) % 5, ij = idx / 45;
        float acc = 0.f;
        for (int k2 = 0; k2 < 20; k2++)
            acc = fmaf(W1_sso[ij * 20 + k2], W2_sso[(k2 * 5 + j3) * 9 + o], acc);
        ws[WS_W12 + idx] = acc * (I21 * I105);
    }
    for (int idx = tid; idx < 45; idx += 256) {
        int o = idx % 9, j3 = idx / 9;
        float acc = 0.f;
        for (int k2 = 0; k2 < 20; k2++)
            acc = fmaf(W1_vvo[k2], W2_sso[(k2 * 5 + j3) * 9 + o], acc);
        ws[WS_WV + idx] = acc * (I21 * I105 * I3);
    }
    for (int idx = tid; idx < 20; idx += 256) {
        float acc = 0.f;
        for (int k2 = 0; k2 < 20; k2++)
            acc = fmaf(W1_sso[idx * 20 + k2], W2_svv[k2], acc);
        ws[WS_WS + idx] = acc * (I21 * I50);
    }
    if (tid == 0) {
        float acc = 0.f;
        for (int k2 = 0; k2 < 20; k2++) acc = fmaf(W1_vvo[k2], W2_svv[k2], acc);
        ws[WS_CS] = acc * (I21 * I50 * I3);
    }
    for (int idx = tid; idx < 25; idx += 256) ws[WS_SVV + idx] = W1_svv[idx] * I10;
    for (int idx = tid; idx < 20; idx += 256) ws[WS_VSV + idx] = W1_vsv[idx] * I10;
    for (int idx = tid; idx < 5; idx += 256)  ws[WS_VVV1 + idx] = W1_vvv[idx] * (I10 * I2);
    for (int idx = tid; idx < 25; idx += 256) ws[WS_VSV2 + idx] = W2_vsv[idx] * I50;
    for (int idx = tid; idx < 5; idx += 256)  ws[WS_VVV2 + idx] = W2_vvv[idx] * (I2 * I50);
    for (int idx = tid; idx < 45; idx += 256) ws[WS_VVO2 + idx] = W2_vvo[idx] * (I3 * I105);
}

__global__ __launch_bounds__(256) void fds_kernel(
    const float* __restrict__ lig, const float* __restrict__ rec,
    const float* __restrict__ ws, float* __restrict__ out, int E)
{
    const float C5 = -0.32f;          // -0.5 / 1.25^2
    const float C4 = -0.18f;          // -0.5 / (5/3)^2
    const float EK1  = 0.60653065971263342f;   // e^-0.5
    const float EK4  = 0.13533528323661270f;   // e^-2
    const float EK9  = 0.011108996538242306f;  // e^-4.5
    const float EK16 = 3.3546262790251185e-4f; // e^-8

    const float* __restrict__ W12  = ws + WS_W12;
    const float* __restrict__ WV   = ws + WS_WV;
    const float* __restrict__ WSp  = ws + WS_WS;
    const float* __restrict__ SVV  = ws + WS_SVV;
    const float* __restrict__ VSV  = ws + WS_VSV;
    const float* __restrict__ VVV1 = ws + WS_VVV1;
    const float* __restrict__ VSV2 = ws + WS_VSV2;
    const float* __restrict__ VVV2 = ws + WS_VVV2;
    const float* __restrict__ VVO2 = ws + WS_VVO2;

    int t0 = blockIdx.x * blockDim.x + threadIdx.x;
    int stride = gridDim.x * blockDim.x;
    size_t E3 = (size_t)E * 3;

    for (int e = t0; e < E; e += stride) {
        const float4* lp = (const float4*)lig + 3 * (size_t)e;
        const float4* rp = (const float4*)rec + 3 * (size_t)e;
        float4 l0 = lp[0], l1 = lp[1], l2 = lp[2];
        float4 r0 = rp[0], r1 = rp[1], r2 = rp[2];

        float e1x = l0.w - r0.w, e1y = l1.x - r1.x, e1z = l1.y - r1.y;
        float e2x = l1.z - r1.z, e2y = l1.w - r1.w, e2z = l2.x - r2.x;
        float e3x = l2.y - r2.y, e3y = l2.z - r2.z, e3z = l2.w - r2.w;

        float q1 = fmaf(e1x, e1x, fmaf(e1y, e1y, e1z * e1z)) + 1e-12f;
        float q2 = fmaf(e2x, e2x, fmaf(e2y, e2y, e2z * e2z)) + 1e-12f;
        float q3 = fmaf(e3x, e3x, fmaf(e3y, e3y, e3z * e3z)) + 1e-12f;
        float ri1 = rsqrtf(q1), ri2 = rsqrtf(q2), ri3 = rsqrtf(q3);
        float d1 = q1 * ri1, d2 = q2 * ri2, d3 = q3 * ri3;
        float v1x = e1x * ri1, v1y = e1y * ri1, v1z = e1z * ri1;
        float v2x = e2x * ri2, v2y = e2y * ri2, v2z = e2z * ri2;
        float v3x = e3x * ri3, v3y = e3y * ri3, v3z = e3z * ri3;

        // smear: s[i] = exp(C*(d - h*i)^2) = E0 * r^i * K[i^2]
        float s1[5], s3[5], s2[4];
        {
            float E0 = __expf(C5 * d1 * d1), r = __expf(0.8f * d1);
            float rr = r * r, u = E0 * r, v = E0 * rr;
            s1[0] = E0; s1[1] = u * EK1; s1[2] = v * EK4;
            s1[3] = v * r * EK9; s1[4] = v * rr * EK16;
        }
        {
            float E0 = __expf(C5 * d3 * d3), r = __expf(0.8f * d3);
            float rr = r * r, u = E0 * r, v = E0 * rr;
            s3[0] = E0; s3[1] = u * EK1; s3[2] = v * EK4;
            s3[3] = v * r * EK9; s3[4] = v * rr * EK16;
        }
        {
            float E0 = __expf(C4 * d2 * d2), r = __expf(0.6f * d2);
            float rr = r * r;
            s2[0] = E0; s2[1] = E0 * r * EK1; s2[2] = E0 * rr * EK4;
            s2[3] = E0 * rr * r * EK9;
        }

        float dot12 = fmaf(v1x, v2x, fmaf(v1y, v2y, v1z * v2z));  // raw
        float cr12x = v1y * v2z - v1z * v2y;                       // raw
        float cr12y = v1z * v2x - v1x * v2z;
        float cr12z = v1x * v2y - v1y * v2x;

        // layer 1 vector path (scales folded into SVV/VSV/VVV1)
        float A[5], B[5];
#pragma unroll
        for (int k = 0; k < 5; k++) {
            float a = 0.f, b = 0.f;
#pragma unroll
            for (int i = 0; i < 5; i++) a = fmaf(s1[i], SVV[i * 5 + k], a);
#pragma unroll
            for (int j = 0; j < 4; j++) b = fmaf(s2[j], VSV[j * 5 + k], b);
            A[k] = a; B[k] = b;
        }
        float ov[5][3];
#pragma unroll
        for (int k = 0; k < 5; k++) {
            float w = VVV1[k];
            ov[k][0] = fmaf(A[k], v2x, fmaf(B[k], v1x, cr12x * w));
            ov[k][1] = fmaf(A[k], v2y, fmaf(B[k], v1y, cr12y * w));
            ov[k][2] = fmaf(A[k], v2z, fmaf(B[k], v1z, cr12z * w));
        }

        float dot2[5];
#pragma unroll
        for (int k = 0; k < 5; k++)
            dot2[k] = fmaf(ov[k][0], v3x, fmaf(ov[k][1], v3y, ov[k][2] * v3z)); // raw

        float accs[9];
#pragma unroll
        for (int o = 0; o < 9; o++) accs[o] = 0.f;
#pragma unroll
        for (int k = 0; k < 5; k++)
#pragma unroll
            for (int o = 0; o < 9; o++) accs[o] = fmaf(dot2[k], VVO2[k * 9 + o], accs[o]);

        float av0 = 0.f, av1 = 0.f, av2 = 0.f;
#pragma unroll
        for (int k = 0; k < 5; k++) {
            float c = 0.f;
#pragma unroll
            for (int j = 0; j < 5; j++) c = fmaf(s3[j], VSV2[k * 5 + j], c);
            float w = VVV2[k];
            float cx = ov[k][1] * v3z - ov[k][2] * v3y;  // raw cross
            float cy = ov[k][2] * v3x - ov[k][0] * v3z;
            float cz = ov[k][0] * v3y - ov[k][1] * v3x;
            av0 = fmaf(ov[k][0], c, fmaf(cx, w, av0));
            av1 = fmaf(ov[k][1], c, fmaf(cy, w, av1));
            av2 = fmaf(ov[k][2], c, fmaf(cz, w, av2));
        }
        // ov dead from here

        float p12[20];
#pragma unroll
        for (int i = 0; i < 5; i++)
#pragma unroll
            for (int j = 0; j < 4; j++) p12[i * 4 + j] = s1[i] * s2[j];

        float S = dot12 * ws[WS_CS];
#pragma unroll
        for (int ij = 0; ij < 20; ij++) S = fmaf(p12[ij], WSp[ij], S);
        av0 = fmaf(S, v3x, av0);
        av1 = fmaf(S, v3y, av1);
        av2 = fmaf(S, v3z, av2);

#pragma unroll
        for (int j3 = 0; j3 < 5; j3++) {
            float fv = dot12 * s3[j3];
            const float* w = WV + j3 * 9;
#pragma unroll
            for (int o = 0; o < 9; o++) accs[o] = fmaf(fv, w[o], accs[o]);
        }
#pragma unroll
        for (int ij = 0; ij < 20; ij++) {
            float p = p12[ij];
#pragma unroll
            for (int j3 = 0; j3 < 5; j3++) {
                float f = p * s3[j3];
                const float* w = W12 + (ij * 5 + j3) * 9;
#pragma unroll
                for (int o = 0; o < 9; o++) accs[o] = fmaf(f, w[o], accs[o]);
            }
        }

        size_t b = (size_t)e * 3;
        out[b + 0]          = accs[0];   // s_rot
        out[b + 1]          = accs[1];
        out[b + 2]          = accs[2];
        out[E3 + b + 0]     = accs[3];   // s_tr
        out[E3 + b + 1]     = accs[4];
        out[E3 + b + 2]     = accs[5];
        out[2 * E3 + b + 0] = accs[6];   // t_rot
        out[2 * E3 + b + 1] = accs[7];
        out[2 * E3 + b + 2] = accs[8];
        out[3 * E3 + b + 0] = av0;       // t_tr
        out[3 * E3 + b + 1] = av1;
        out[3 * E3 + b + 2] = av2;
    }
}

extern "C" void kernel_launch(void* const* d_in, const int* in_sizes, int n_in,
                              void* d_out, int out_size, void* d_ws, size_t ws_size,
                              hipStream_t stream) {
    const float* lig    = (const float*)d_in[0];
    const float* rec    = (const float*)d_in[1];
    const float* W1_sso = (const float*)d_in[2];
    const float* W1_svv = (const float*)d_in[3];
    const float* W1_vsv = (const float*)d_in[4];
    const float* W1_vvo = (const float*)d_in[5];
    const float* W1_vvv = (const float*)d_in[6];
    const float* W2_sso = (const float*)d_in[7];
    const float* W2_svv = (const float*)d_in[8];
    const float* W2_vsv = (const float*)d_in[9];
    const float* W2_vvo = (const float*)d_in[10];
    const float* W2_vvv = (const float*)d_in[11];
    float* ws = (float*)d_ws;

    fds_precompose<<<1, 256, 0, stream>>>(W1_sso, W1_svv, W1_vsv, W1_vvo, W1_vvv,
                                          W2_sso, W2_svv, W2_vsv, W2_vvo, W2_vvv, ws);

    int E = in_sizes[0] / 12;  // N*3 / 12 = N/4
    int blocks = (E + 255) / 256;
    if (blocks > 2048) blocks = 2048;   // 8 blocks/CU x 256 CU, grid-stride
    fds_kernel<<<blocks, 256, 0, stream>>>(lig, rec, ws, (float*)d_out, E);
}

// Round 7
// 59.741 us; speedup vs baseline: 2.1891x; 2.0235x over previous
//
#include <hip/hip_runtime.h>
#include <math.h>

// R4's proven flat structure (1 thread/edge, 3907 blocks, VGPR~36, no spills)
// + the two pure-VALU wins from R5/R6:
//   (a) all scale constants folded into precomposed weight copies in d_ws
//   (b) smear exp factorization: s[i] = E0 * r^i * K[i^2] (6 exps, not 14)
// Each folded weight region passed as its own __restrict__ arg (R4 style).
// Grid-stride persistent loop REVERTED (R6: VGPR 36->80, occupancy 45->28%,
// 2x dur — flat short blocks schedule better on gfx950 here).

#define WS_W12  0     // [20][5][9] *i21*i105          = 900
#define WS_WV   900   // [5][9]     *i21*i105*i3       = 45
#define WS_WS   945   // [20]       *i21*i50           = 20
#define WS_CS   965   // scalar     *i21*i50*i3        = 1
#define WS_SVV  966   // [5][5]     *i10               = 25
#define WS_VSV  991   // [4][5]     *i10               = 20
#define WS_VVV1 1011  // [5]        *i10*i2            = 5
#define WS_VSV2 1016  // [5][5]     *i50               = 25
#define WS_VVV2 1041  // [5]        *i2*i50            = 5
#define WS_VVO2 1046  // [5][9]     *i3*i105           = 45
#define WS_TOT  1091

__global__ __launch_bounds__(256) void fds_precompose(
    const float* __restrict__ W1_sso, const float* __restrict__ W1_svv,
    const float* __restrict__ W1_vsv, const float* __restrict__ W1_vvo,
    const float* __restrict__ W1_vvv, const float* __restrict__ W2_sso,
    const float* __restrict__ W2_svv, const float* __restrict__ W2_vsv,
    const float* __restrict__ W2_vvo, const float* __restrict__ W2_vvv,
    float* __restrict__ ws)
{
    const float I2 = 0.70710678118654752f, I3 = 0.57735026918962576f;
    const float I10 = 0.31622776601683794f, I21 = 0.21821789023599239f;
    const float I105 = 0.09759000729485332f, I50 = 0.14142135623730950f;
    int tid = threadIdx.x;
    for (int idx = tid; idx < 900; idx += 256) {
        int o = idx % 9, j3 = (idx / 9) % 5, ij = idx / 45;
        float acc = 0.f;
        for (int k2 = 0; k2 < 20; k2++)
            acc = fmaf(W1_sso[ij * 20 + k2], W2_sso[(k2 * 5 + j3) * 9 + o], acc);
        ws[WS_W12 + idx] = acc * (I21 * I105);
    }
    for (int idx = tid; idx < 45; idx += 256) {
        int o = idx % 9, j3 = idx / 9;
        float acc = 0.f;
        for (int k2 = 0; k2 < 20; k2++)
            acc = fmaf(W1_vvo[k2], W2_sso[(k2 * 5 + j3) * 9 + o], acc);
        ws[WS_WV + idx] = acc * (I21 * I105 * I3);
    }
    for (int idx = tid; idx < 20; idx += 256) {
        float acc = 0.f;
        for (int k2 = 0; k2 < 20; k2++)
            acc = fmaf(W1_sso[idx * 20 + k2], W2_svv[k2], acc);
        ws[WS_WS + idx] = acc * (I21 * I50);
    }
    if (tid == 0) {
        float acc = 0.f;
        for (int k2 = 0; k2 < 20; k2++) acc = fmaf(W1_vvo[k2], W2_svv[k2], acc);
        ws[WS_CS] = acc * (I21 * I50 * I3);
    }
    for (int idx = tid; idx < 25; idx += 256) ws[WS_SVV + idx] = W1_svv[idx] * I10;
    for (int idx = tid; idx < 20; idx += 256) ws[WS_VSV + idx] = W1_vsv[idx] * I10;
    for (int idx = tid; idx < 5; idx += 256)  ws[WS_VVV1 + idx] = W1_vvv[idx] * (I10 * I2);
    for (int idx = tid; idx < 25; idx += 256) ws[WS_VSV2 + idx] = W2_vsv[idx] * I50;
    for (int idx = tid; idx < 5; idx += 256)  ws[WS_VVV2 + idx] = W2_vvv[idx] * (I2 * I50);
    for (int idx = tid; idx < 45; idx += 256) ws[WS_VVO2 + idx] = W2_vvo[idx] * (I3 * I105);
}

__global__ __launch_bounds__(256) void fds_kernel(
    const float* __restrict__ lig, const float* __restrict__ rec,
    const float* __restrict__ W12, const float* __restrict__ WV,
    const float* __restrict__ WSp, const float* __restrict__ CSp,
    const float* __restrict__ SVV, const float* __restrict__ VSV,
    const float* __restrict__ VVV1, const float* __restrict__ VSV2,
    const float* __restrict__ VVV2, const float* __restrict__ VVO2,
    float* __restrict__ out, int E)
{
    const float C5 = -0.32f;          // -0.5 / 1.25^2
    const float C4 = -0.18f;          // -0.5 / (5/3)^2
    const float EK1  = 0.60653065971263342f;   // e^-0.5
    const float EK4  = 0.13533528323661270f;   // e^-2
    const float EK9  = 0.011108996538242306f;  // e^-4.5
    const float EK16 = 3.3546262790251185e-4f; // e^-8

    int e = blockIdx.x * blockDim.x + threadIdx.x;
    if (e >= E) return;

    const float4* lp = (const float4*)lig + 3 * (size_t)e;
    const float4* rp = (const float4*)rec + 3 * (size_t)e;
    float4 l0 = lp[0], l1 = lp[1], l2 = lp[2];
    float4 r0 = rp[0], r1 = rp[1], r2 = rp[2];

    // row 4e+1 = floats 3..5, row 4e+2 = floats 6..8, row 4e+3 = floats 9..11
    float e1x = l0.w - r0.w, e1y = l1.x - r1.x, e1z = l1.y - r1.y;
    float e2x = l1.z - r1.z, e2y = l1.w - r1.w, e2z = l2.x - r2.x;
    float e3x = l2.y - r2.y, e3y = l2.z - r2.z, e3z = l2.w - r2.w;

    float q1 = fmaf(e1x, e1x, fmaf(e1y, e1y, e1z * e1z)) + 1e-12f;
    float q2 = fmaf(e2x, e2x, fmaf(e2y, e2y, e2z * e2z)) + 1e-12f;
    float q3 = fmaf(e3x, e3x, fmaf(e3y, e3y, e3z * e3z)) + 1e-12f;
    float ri1 = rsqrtf(q1), ri2 = rsqrtf(q2), ri3 = rsqrtf(q3);
    float d1 = q1 * ri1, d2 = q2 * ri2, d3 = q3 * ri3;
    float v1x = e1x * ri1, v1y = e1y * ri1, v1z = e1z * ri1;
    float v2x = e2x * ri2, v2y = e2y * ri2, v2z = e2z * ri2;
    float v3x = e3x * ri3, v3y = e3y * ri3, v3z = e3z * ri3;

    // smear: s[i] = exp(C*(d - h*i)^2) = E0 * r^i * K[i^2]
    float s1[5], s3[5], s2[4];
    {
        float E0 = __expf(C5 * d1 * d1), r = __expf(0.8f * d1);
        float rr = r * r, u = E0 * r, v = E0 * rr;
        s1[0] = E0; s1[1] = u * EK1; s1[2] = v * EK4;
        s1[3] = v * r * EK9; s1[4] = v * rr * EK16;
    }
    {
        float E0 = __expf(C5 * d3 * d3), r = __expf(0.8f * d3);
        float rr = r * r, u = E0 * r, v = E0 * rr;
        s3[0] = E0; s3[1] = u * EK1; s3[2] = v * EK4;
        s3[3] = v * r * EK9; s3[4] = v * rr * EK16;
    }
    {
        float E0 = __expf(C4 * d2 * d2), r = __expf(0.6f * d2);
        float rr = r * r;
        s2[0] = E0; s2[1] = E0 * r * EK1; s2[2] = E0 * rr * EK4;
        s2[3] = E0 * rr * r * EK9;
    }

    float dot12 = fmaf(v1x, v2x, fmaf(v1y, v2y, v1z * v2z));  // raw
    float cr12x = v1y * v2z - v1z * v2y;                       // raw
    float cr12y = v1z * v2x - v1x * v2z;
    float cr12z = v1x * v2y - v1y * v2x;

    // layer 1 vector path (scales folded into SVV/VSV/VVV1)
    float A[5], B[5];
#pragma unroll
    for (int k = 0; k < 5; k++) {
        float a = 0.f, b = 0.f;
#pragma unroll
        for (int i = 0; i < 5; i++) a = fmaf(s1[i], SVV[i * 5 + k], a);
#pragma unroll
        for (int j = 0; j < 4; j++) b = fmaf(s2[j], VSV[j * 5 + k], b);
        A[k] = a; B[k] = b;
    }
    float ov[5][3];
#pragma unroll
    for (int k = 0; k < 5; k++) {
        float w = VVV1[k];
        ov[k][0] = fmaf(A[k], v2x, fmaf(B[k], v1x, cr12x * w));
        ov[k][1] = fmaf(A[k], v2y, fmaf(B[k], v1y, cr12y * w));
        ov[k][2] = fmaf(A[k], v2z, fmaf(B[k], v1z, cr12z * w));
    }

    float dot2[5];
#pragma unroll
    for (int k = 0; k < 5; k++)
        dot2[k] = fmaf(ov[k][0], v3x, fmaf(ov[k][1], v3y, ov[k][2] * v3z)); // raw

    float accs[9];
#pragma unroll
    for (int o = 0; o < 9; o++) accs[o] = 0.f;
#pragma unroll
    for (int k = 0; k < 5; k++)
#pragma unroll
        for (int o = 0; o < 9; o++) accs[o] = fmaf(dot2[k], VVO2[k * 9 + o], accs[o]);

    float av0 = 0.f, av1 = 0.f, av2 = 0.f;
#pragma unroll
    for (int k = 0; k < 5; k++) {
        float c = 0.f;
#pragma unroll
        for (int j = 0; j < 5; j++) c = fmaf(s3[j], VSV2[k * 5 + j], c);
        float w = VVV2[k];
        float cx = ov[k][1] * v3z - ov[k][2] * v3y;  // raw cross
        float cy = ov[k][2] * v3x - ov[k][0] * v3z;
        float cz = ov[k][0] * v3y - ov[k][1] * v3x;
        av0 = fmaf(ov[k][0], c, fmaf(cx, w, av0));
        av1 = fmaf(ov[k][1], c, fmaf(cy, w, av1));
        av2 = fmaf(ov[k][2], c, fmaf(cz, w, av2));
    }
    // ov dead from here

    float p12[20];
#pragma unroll
    for (int i = 0; i < 5; i++)
#pragma unroll
        for (int j = 0; j < 4; j++) p12[i * 4 + j] = s1[i] * s2[j];

    float S = dot12 * CSp[0];
#pragma unroll
    for (int ij = 0; ij < 20; ij++) S = fmaf(p12[ij], WSp[ij], S);
    av0 = fmaf(S, v3x, av0);
    av1 = fmaf(S, v3y, av1);
    av2 = fmaf(S, v3z, av2);

#pragma unroll
    for (int j3 = 0; j3 < 5; j3++) {
        float fv = dot12 * s3[j3];
        const float* w = WV + j3 * 9;
#pragma unroll
        for (int o = 0; o < 9; o++) accs[o] = fmaf(fv, w[o], accs[o]);
    }
#pragma unroll
    for (int ij = 0; ij < 20; ij++) {
        float p = p12[ij];
#pragma unroll
        for (int j3 = 0; j3 < 5; j3++) {
            float f = p * s3[j3];
            const float* w = W12 + (ij * 5 + j3) * 9;
#pragma unroll
            for (int o = 0; o < 9; o++) accs[o] = fmaf(f, w[o], accs[o]);
        }
    }

    size_t E3 = (size_t)E * 3;
    size_t b = (size_t)e * 3;
    out[b + 0]          = accs[0];   // s_rot
    out[b + 1]          = accs[1];
    out[b + 2]          = accs[2];
    out[E3 + b + 0]     = accs[3];   // s_tr
    out[E3 + b + 1]     = accs[4];
    out[E3 + b + 2]     = accs[5];
    out[2 * E3 + b + 0] = accs[6];   // t_rot
    out[2 * E3 + b + 1] = accs[7];
    out[2 * E3 + b + 2] = accs[8];
    out[3 * E3 + b + 0] = av0;       // t_tr
    out[3 * E3 + b + 1] = av1;
    out[3 * E3 + b + 2] = av2;
}

extern "C" void kernel_launch(void* const* d_in, const int* in_sizes, int n_in,
                              void* d_out, int out_size, void* d_ws, size_t ws_size,
                              hipStream_t stream) {
    const float* lig    = (const float*)d_in[0];
    const float* rec    = (const float*)d_in[1];
    const float* W1_sso = (const float*)d_in[2];
    const float* W1_svv = (const float*)d_in[3];
    const float* W1_vsv = (const float*)d_in[4];
    const float* W1_vvo = (const float*)d_in[5];
    const float* W1_vvv = (const float*)d_in[6];
    const float* W2_sso = (const float*)d_in[7];
    const float* W2_svv = (const float*)d_in[8];
    const float* W2_vsv = (const float*)d_in[9];
    const float* W2_vvo = (const float*)d_in[10];
    const float* W2_vvv = (const float*)d_in[11];
    float* ws = (float*)d_ws;

    fds_precompose<<<1, 256, 0, stream>>>(W1_sso, W1_svv, W1_vsv, W1_vvo, W1_vvv,
                                          W2_sso, W2_svv, W2_vsv, W2_vvo, W2_vvv, ws);

    int E = in_sizes[0] / 12;  // N*3 / 12 = N/4
    int blocks = (E + 255) / 256;
    fds_kernel<<<blocks, 256, 0, stream>>>(
        lig, rec,
        ws + WS_W12, ws + WS_WV, ws + WS_WS, ws + WS_CS,
        ws + WS_SVV, ws + WS_VSV, ws + WS_VVV1, ws + WS_VSV2,
        ws + WS_VVV2, ws + WS_VVO2,
        (float*)d_out, E);
}

// Round 8
// 52.191 us; speedup vs baseline: 2.5058x; 1.1447x over previous
//
#include <hip/hip_runtime.h>
#include <math.h>

// R7 + the W12/WV contraction converted to a REAL (non-unrolled) loop over j3
// with loop-carried s3 (s3_{j+1} = s3_j * u; u *= e^-1). Purpose: halve static
// code size (I$ probe) and batch the weight s_load stream per j3 iteration.
// All array indices inside the loop are compile-time (p12, accs) -> no scratch.

#define WS_W12  0     // [20][5][9] *i21*i105          = 900
#define WS_WV   900   // [5][9]     *i21*i105*i3       = 45
#define WS_WS   945   // [20]       *i21*i50           = 20
#define WS_CS   965   // scalar     *i21*i50*i3        = 1
#define WS_SVV  966   // [5][5]     *i10               = 25
#define WS_VSV  991   // [4][5]     *i10               = 20
#define WS_VVV1 1011  // [5]        *i10*i2            = 5
#define WS_VSV2 1016  // [5][5]     *i50               = 25
#define WS_VVV2 1041  // [5]        *i2*i50            = 5
#define WS_VVO2 1046  // [5][9]     *i3*i105           = 45
#define WS_TOT  1091

__global__ __launch_bounds__(256) void fds_precompose(
    const float* __restrict__ W1_sso, const float* __restrict__ W1_svv,
    const float* __restrict__ W1_vsv, const float* __restrict__ W1_vvo,
    const float* __restrict__ W1_vvv, const float* __restrict__ W2_sso,
    const float* __restrict__ W2_svv, const float* __restrict__ W2_vsv,
    const float* __restrict__ W2_vvo, const float* __restrict__ W2_vvv,
    float* __restrict__ ws)
{
    const float I2 = 0.70710678118654752f, I3 = 0.57735026918962576f;
    const float I10 = 0.31622776601683794f, I21 = 0.21821789023599239f;
    const float I105 = 0.09759000729485332f, I50 = 0.14142135623730950f;
    int tid = threadIdx.x;
    for (int idx = tid; idx < 900; idx += 256) {
        int o = idx % 9, j3 = (idx / 9) % 5, ij = idx / 45;
        float acc = 0.f;
        for (int k2 = 0; k2 < 20; k2++)
            acc = fmaf(W1_sso[ij * 20 + k2], W2_sso[(k2 * 5 + j3) * 9 + o], acc);
        ws[WS_W12 + idx] = acc * (I21 * I105);
    }
    for (int idx = tid; idx < 45; idx += 256) {
        int o = idx % 9, j3 = idx / 9;
        float acc = 0.f;
        for (int k2 = 0; k2 < 20; k2++)
            acc = fmaf(W1_vvo[k2], W2_sso[(k2 * 5 + j3) * 9 + o], acc);
        ws[WS_WV + idx] = acc * (I21 * I105 * I3);
    }
    for (int idx = tid; idx < 20; idx += 256) {
        float acc = 0.f;
        for (int k2 = 0; k2 < 20; k2++)
            acc = fmaf(W1_sso[idx * 20 + k2], W2_svv[k2], acc);
        ws[WS_WS + idx] = acc * (I21 * I50);
    }
    if (tid == 0) {
        float acc = 0.f;
        for (int k2 = 0; k2 < 20; k2++) acc = fmaf(W1_vvo[k2], W2_svv[k2], acc);
        ws[WS_CS] = acc * (I21 * I50 * I3);
    }
    for (int idx = tid; idx < 25; idx += 256) ws[WS_SVV + idx] = W1_svv[idx] * I10;
    for (int idx = tid; idx < 20; idx += 256) ws[WS_VSV + idx] = W1_vsv[idx] * I10;
    for (int idx = tid; idx < 5; idx += 256)  ws[WS_VVV1 + idx] = W1_vvv[idx] * (I10 * I2);
    for (int idx = tid; idx < 25; idx += 256) ws[WS_VSV2 + idx] = W2_vsv[idx] * I50;
    for (int idx = tid; idx < 5; idx += 256)  ws[WS_VVV2 + idx] = W2_vvv[idx] * (I2 * I50);
    for (int idx = tid; idx < 45; idx += 256) ws[WS_VVO2 + idx] = W2_vvo[idx] * (I3 * I105);
}

__global__ __launch_bounds__(256) void fds_kernel(
    const float* __restrict__ lig, const float* __restrict__ rec,
    const float* __restrict__ W12, const float* __restrict__ WV,
    const float* __restrict__ WSp, const float* __restrict__ CSp,
    const float* __restrict__ SVV, const float* __restrict__ VSV,
    const float* __restrict__ VVV1, const float* __restrict__ VSV2,
    const float* __restrict__ VVV2, const float* __restrict__ VVO2,
    float* __restrict__ out, int E)
{
    const float C5 = -0.32f;          // -0.5 / 1.25^2
    const float C4 = -0.18f;          // -0.5 / (5/3)^2
    const float EK1  = 0.60653065971263342f;   // e^-0.5
    const float EK4  = 0.13533528323661270f;   // e^-2
    const float EK9  = 0.011108996538242306f;  // e^-4.5
    const float EK16 = 3.3546262790251185e-4f; // e^-8
    const float EM1  = 0.36787944117144233f;   // e^-1

    int e = blockIdx.x * blockDim.x + threadIdx.x;
    if (e >= E) return;

    const float4* lp = (const float4*)lig + 3 * (size_t)e;
    const float4* rp = (const float4*)rec + 3 * (size_t)e;
    float4 l0 = lp[0], l1 = lp[1], l2 = lp[2];
    float4 r0 = rp[0], r1 = rp[1], r2 = rp[2];

    // row 4e+1 = floats 3..5, row 4e+2 = floats 6..8, row 4e+3 = floats 9..11
    float e1x = l0.w - r0.w, e1y = l1.x - r1.x, e1z = l1.y - r1.y;
    float e2x = l1.z - r1.z, e2y = l1.w - r1.w, e2z = l2.x - r2.x;
    float e3x = l2.y - r2.y, e3y = l2.z - r2.z, e3z = l2.w - r2.w;

    float q1 = fmaf(e1x, e1x, fmaf(e1y, e1y, e1z * e1z)) + 1e-12f;
    float q2 = fmaf(e2x, e2x, fmaf(e2y, e2y, e2z * e2z)) + 1e-12f;
    float q3 = fmaf(e3x, e3x, fmaf(e3y, e3y, e3z * e3z)) + 1e-12f;
    float ri1 = rsqrtf(q1), ri2 = rsqrtf(q2), ri3 = rsqrtf(q3);
    float d1 = q1 * ri1, d2 = q2 * ri2, d3 = q3 * ri3;
    float v1x = e1x * ri1, v1y = e1y * ri1, v1z = e1z * ri1;
    float v2x = e2x * ri2, v2y = e2y * ri2, v2z = e2z * ri2;
    float v3x = e3x * ri3, v3y = e3y * ri3, v3z = e3z * ri3;

    // smear: s[i] = exp(C*(d - h*i)^2) = E0 * r^i * K[i^2]
    float s1[5], s3[5], s2[4];
    float r3;
    {
        float E0 = __expf(C5 * d1 * d1), r = __expf(0.8f * d1);
        float rr = r * r, u = E0 * r, v = E0 * rr;
        s1[0] = E0; s1[1] = u * EK1; s1[2] = v * EK4;
        s1[3] = v * r * EK9; s1[4] = v * rr * EK16;
    }
    {
        float E0 = __expf(C5 * d3 * d3); r3 = __expf(0.8f * d3);
        float rr = r3 * r3, u = E0 * r3, v = E0 * rr;
        s3[0] = E0; s3[1] = u * EK1; s3[2] = v * EK4;
        s3[3] = v * r3 * EK9; s3[4] = v * rr * EK16;
    }
    {
        float E0 = __expf(C4 * d2 * d2), r = __expf(0.6f * d2);
        float rr = r * r;
        s2[0] = E0; s2[1] = E0 * r * EK1; s2[2] = E0 * rr * EK4;
        s2[3] = E0 * rr * r * EK9;
    }

    float dot12 = fmaf(v1x, v2x, fmaf(v1y, v2y, v1z * v2z));  // raw
    float cr12x = v1y * v2z - v1z * v2y;                       // raw
    float cr12y = v1z * v2x - v1x * v2z;
    float cr12z = v1x * v2y - v1y * v2x;

    // layer 1 vector path (scales folded into SVV/VSV/VVV1)
    float A[5], B[5];
#pragma unroll
    for (int k = 0; k < 5; k++) {
        float a = 0.f, b = 0.f;
#pragma unroll
        for (int i = 0; i < 5; i++) a = fmaf(s1[i], SVV[i * 5 + k], a);
#pragma unroll
        for (int j = 0; j < 4; j++) b = fmaf(s2[j], VSV[j * 5 + k], b);
        A[k] = a; B[k] = b;
    }
    float ov[5][3];
#pragma unroll
    for (int k = 0; k < 5; k++) {
        float w = VVV1[k];
        ov[k][0] = fmaf(A[k], v2x, fmaf(B[k], v1x, cr12x * w));
        ov[k][1] = fmaf(A[k], v2y, fmaf(B[k], v1y, cr12y * w));
        ov[k][2] = fmaf(A[k], v2z, fmaf(B[k], v1z, cr12z * w));
    }

    float dot2[5];
#pragma unroll
    for (int k = 0; k < 5; k++)
        dot2[k] = fmaf(ov[k][0], v3x, fmaf(ov[k][1], v3y, ov[k][2] * v3z)); // raw

    float accs[9];
#pragma unroll
    for (int o = 0; o < 9; o++) accs[o] = 0.f;
#pragma unroll
    for (int k = 0; k < 5; k++)
#pragma unroll
        for (int o = 0; o < 9; o++) accs[o] = fmaf(dot2[k], VVO2[k * 9 + o], accs[o]);

    float av0 = 0.f, av1 = 0.f, av2 = 0.f;
#pragma unroll
    for (int k = 0; k < 5; k++) {
        float c = 0.f;
#pragma unroll
        for (int j = 0; j < 5; j++) c = fmaf(s3[j], VSV2[k * 5 + j], c);
        float w = VVV2[k];
        float cx = ov[k][1] * v3z - ov[k][2] * v3y;  // raw cross
        float cy = ov[k][2] * v3x - ov[k][0] * v3z;
        float cz = ov[k][0] * v3y - ov[k][1] * v3x;
        av0 = fmaf(ov[k][0], c, fmaf(cx, w, av0));
        av1 = fmaf(ov[k][1], c, fmaf(cy, w, av1));
        av2 = fmaf(ov[k][2], c, fmaf(cz, w, av2));
    }
    // ov dead from here

    float p12[20];
#pragma unroll
    for (int i = 0; i < 5; i++)
#pragma unroll
        for (int j = 0; j < 4; j++) p12[i * 4 + j] = s1[i] * s2[j];

    float S = dot12 * CSp[0];
#pragma unroll
    for (int ij = 0; ij < 20; ij++) S = fmaf(p12[ij], WSp[ij], S);
    av0 = fmaf(S, v3x, av0);
    av1 = fmaf(S, v3y, av1);
    av2 = fmaf(S, v3z, av2);

    // ---- j3-loop (NOT unrolled): accs[o] += (p12[ij]*s3[j3])*W12[ij*45+j3*9+o]
    //                                      + (dot12*s3[j3])*WV[j3*9+o]
    // s3[j3] loop-carried: s3c *= uu; uu *= e^-1  (uu0 = r3 * e^-0.5)
    {
        const float* wj = W12;
        const float* wv = WV;
        float s3c = s3[0];
        float uu = r3 * EK1;
#pragma clang loop unroll(disable)
        for (int j3 = 0; j3 < 5; ++j3) {
            float fv = dot12 * s3c;
#pragma unroll
            for (int o = 0; o < 9; o++) accs[o] = fmaf(fv, wv[o], accs[o]);
#pragma unroll
            for (int ij = 0; ij < 20; ij++) {
                float f = p12[ij] * s3c;
#pragma unroll
                for (int o = 0; o < 9; o++)
                    accs[o] = fmaf(f, wj[ij * 45 + o], accs[o]);
            }
            s3c *= uu; uu *= EM1;
            wj += 9; wv += 9;
        }
    }

    size_t E3 = (size_t)E * 3;
    size_t b = (size_t)e * 3;
    out[b + 0]          = accs[0];   // s_rot
    out[b + 1]          = accs[1];
    out[b + 2]          = accs[2];
    out[E3 + b + 0]     = accs[3];   // s_tr
    out[E3 + b + 1]     = accs[4];
    out[E3 + b + 2]     = accs[5];
    out[2 * E3 + b + 0] = accs[6];   // t_rot
    out[2 * E3 + b + 1] = accs[7];
    out[2 * E3 + b + 2] = accs[8];
    out[3 * E3 + b + 0] = av0;       // t_tr
    out[3 * E3 + b + 1] = av1;
    out[3 * E3 + b + 2] = av2;
}

extern "C" void kernel_launch(void* const* d_in, const int* in_sizes, int n_in,
                              void* d_out, int out_size, void* d_ws, size_t ws_size,
                              hipStream_t stream) {
    const float* lig    = (const float*)d_in[0];
    const float* rec    = (const float*)d_in[1];
    const float* W1_sso = (const float*)d_in[2];
    const float* W1_svv = (const float*)d_in[3];
    const float* W1_vsv = (const float*)d_in[4];
    const float* W1_vvo = (const float*)d_in[5];
    const float* W1_vvv = (const float*)d_in[6];
    const float* W2_sso = (const float*)d_in[7];
    const float* W2_svv = (const float*)d_in[8];
    const float* W2_vsv = (const float*)d_in[9];
    const float* W2_vvo = (const float*)d_in[10];
    const float* W2_vvv = (const float*)d_in[11];
    float* ws = (float*)d_ws;

    fds_precompose<<<1, 256, 0, stream>>>(W1_sso, W1_svv, W1_vsv, W1_vvo, W1_vvv,
                                          W2_sso, W2_svv, W2_vsv, W2_vvo, W2_vvv, ws);

    int E = in_sizes[0] / 12;  // N*3 / 12 = N/4
    int blocks = (E + 255) / 256;
    fds_kernel<<<blocks, 256, 0, stream>>>(
        lig, rec,
        ws + WS_W12, ws + WS_WV, ws + WS_WS, ws + WS_CS,
        ws + WS_SVV, ws + WS_VSV, ws + WS_VVV1, ws + WS_VSV2,
        ws + WS_VVV2, ws + WS_VVO2,
        (float*)d_out, E);
}